// Round 6
// baseline (1207.723 us; speedup 1.0000x reference)
//
#include <hip/hip_runtime.h>
#include <stdint.h>

#define NN   16384
#define HID  256
#define LDSK 264            // padded LDS row stride in f16 elems (16B-aligned)
#define NSLICE 8
#define JSL  (NN/NSLICE)    // 2048 j's per slice
#define FLTMAX 3.402823466e38f

typedef __attribute__((ext_vector_type(8))) _Float16 f16x8;
typedef __attribute__((ext_vector_type(4))) _Float16 f16x4;
typedef __attribute__((ext_vector_type(4))) float f32x4;

// ---- fp32 -> fp16 converter ----
__global__ __launch_bounds__(256) void cvt_kernel(const float* __restrict__ in,
                                                  _Float16* __restrict__ out){
  int t = blockIdx.x * 256 + threadIdx.x;
  float4 v = ((const float4*)in)[t];
  f16x4 h; h.x = (_Float16)v.x; h.y = (_Float16)v.y; h.z = (_Float16)v.z; h.w = (_Float16)v.w;
  ((f16x4*)out)[t] = h;
}

// ---- row sum-of-squares, bit-replicating numpy fp32 pairwise summation ----
// numpy n=256: two 128-halves; each: 8 stride-8 accumulators (sequential adds
// i=8..120), combine ((r0+r1)+(r2+r3))+((r4+r5)+(r6+r7)); total = h0 + h1.
// m = xs*xs rounds separately from the add (contract off, NO fma here).
// Lane layout: 16 lanes per row = 2 halves x 8 accumulators; xor-shuffle tree
// reproduces the combine order exactly (fp add is commutative bit-exact).
__global__ __launch_bounds__(256) void sumsq_np_kernel(const float* __restrict__ x,
                                                       float* __restrict__ sqf){
  #pragma clang fp contract(off)
  int lane = threadIdx.x & 63;
  int rw   = lane >> 4;                 // row within wave (4 rows/wave)
  int h    = (lane >> 3) & 1;           // half
  int j    = lane & 7;                  // accumulator index
  int row  = (blockIdx.x * 4 + (threadIdx.x >> 6)) * 4 + rw;
  const float* p = x + (size_t)row * HID + h*128 + j;
  float v0 = p[0];
  float r  = v0 * v0;
  #pragma unroll
  for (int i = 1; i < 16; ++i){ float v = p[i*8]; float m = v * v; r = r + m; }
  float t1 = r  + __shfl_xor(r,  1);
  float t2 = t1 + __shfl_xor(t1, 2);
  float t3 = t2 + __shfl_xor(t2, 4);
  float tot = t3 + __shfl_xor(t3, 8);   // h0 + h1 on h==0 lanes
  if (h == 0 && j == 0) sqf[row] = tot;
}

// stage 64x256 f16 tile into LDS with padded stride (256 threads)
__device__ __forceinline__ void load_tile64(unsigned short* dst, const unsigned short* src, int tid){
  const uint4* s = (const uint4*)src;
  #pragma unroll
  for (int r = 0; r < 8; ++r){
    int fl  = tid + (r << 8);
    int row = fl >> 5;
    int c   = fl & 31;
    *(uint4*)&dst[row*LDSK + (c << 3)] = s[fl];
  }
}

// running top-4 (smallest) insert, strict <
__device__ __forceinline__ void upd4(float (&bd)[4], int (&bi)[4], float d, int j){
  if (d < bd[3]){
    if      (d < bd[0]){ bd[3]=bd[2];bi[3]=bi[2]; bd[2]=bd[1];bi[2]=bi[1]; bd[1]=bd[0];bi[1]=bi[0]; bd[0]=d; bi[0]=j; }
    else if (d < bd[1]){ bd[3]=bd[2];bi[3]=bi[2]; bd[2]=bd[1];bi[2]=bi[1]; bd[1]=d; bi[1]=j; }
    else if (d < bd[2]){ bd[3]=bd[2];bi[3]=bi[2]; bd[2]=d; bi[2]=j; }
    else               { bd[3]=d; bi[3]=j; }
  }
}

// fp16 MFMA Gram, i-tile 128 (32 rows/wave, 2 A-sets per b-frag), j sliced 8-way.
// Top-4 lists live in registers; one LDS merge at block end. Emits 4 candidates
// per (row, slice) -> 32 per row total; exact membership decided by rescore.
__global__ __launch_bounds__(256, 3) void knn_kernel(const _Float16* __restrict__ xh,
                                                     const float* __restrict__ sqf,
                                                     int* __restrict__ cand32){
  __shared__ unsigned short Xj[64 * LDSK];   // 33792 B; reused as merge buffer
  __shared__ float sqj[64];

  int tid  = threadIdx.x;
  int sl   = blockIdx.x & (NSLICE-1);
  int i0   = (blockIdx.x >> 3) * 128;
  int jb0  = sl * JSL;
  int wave = tid >> 6, lane = tid & 63, quad = lane >> 4, lcol = lane & 15;

  // two A-fragment sets: rows i0 + wave*32 + set*16 + lcol
  f16x8 a0[8], a1[8];
  {
    const _Float16* ar0 = xh + (size_t)(i0 + wave*32 +  0 + lcol) * HID + quad*8;
    const _Float16* ar1 = xh + (size_t)(i0 + wave*32 + 16 + lcol) * HID + quad*8;
    #pragma unroll
    for (int ks = 0; ks < 8; ++ks){ a0[ks] = *(const f16x8*)(ar0 + ks*32); a1[ks] = *(const f16x8*)(ar1 + ks*32); }
  }

  float bd[2][4][4]; int bi[2][4][4];
  #pragma unroll
  for (int s = 0; s < 2; ++s)
    #pragma unroll
    for (int r = 0; r < 4; ++r)
      #pragma unroll
      for (int e = 0; e < 4; ++e){ bd[s][r][e] = FLTMAX; bi[s][r][e] = 0; }

  for (int it = 0; it < JSL; it += 64){
    int jb = jb0 + it;
    __syncthreads();
    load_tile64(Xj, (const unsigned short*)(xh + (size_t)jb * HID), tid);
    if (tid < 64) sqj[tid] = sqf[jb + tid];
    __syncthreads();

    #pragma unroll
    for (int sub = 0; sub < 4; ++sub){
      f32x4 acc0 = {0.f,0.f,0.f,0.f}, acc1 = {0.f,0.f,0.f,0.f};
      #pragma unroll
      for (int ks = 0; ks < 8; ++ks){
        f16x8 b = *(const f16x8*)&Xj[(sub*16 + lcol)*LDSK + quad*8 + ks*32];
        acc0 = __builtin_amdgcn_mfma_f32_16x16x32_f16(a0[ks], b, acc0, 0, 0, 0);
        acc1 = __builtin_amdgcn_mfma_f32_16x16x32_f16(a1[ks], b, acc1, 0, 0, 0);
      }
      int   gj = jb + sub*16 + lcol;                   // C/D: col = lane&15
      float sj = sqj[sub*16 + lcol];
      int   ri0 = i0 + wave*32 + quad*4;               // set 0 row base
      #pragma unroll
      for (int reg = 0; reg < 4; ++reg){               // C/D: row = quad*4 + reg
        float v0 = (ri0 + reg == gj)      ? FLTMAX : fmaf(-2.f, acc0[reg], sj);
        float v1 = (ri0 + 16 + reg == gj) ? FLTMAX : fmaf(-2.f, acc1[reg], sj);
        upd4(bd[0][reg], bi[0][reg], v0, gj);
        upd4(bd[1][reg], bi[1][reg], v1, gj);
      }
    }
  }

  // merge: per row, 16 lanes x top-4 -> 64 candidates -> top-4. Two passes of
  // 64 rows each through LDS reused from Xj (64 x 65-dword padded rows x2 arrays).
  float* Md = (float*)Xj;            // 64*65 floats = 16.6 KB
  int*   Mi = (int*)Xj + 64*65;      // +16.6 KB  (total 33.3 KB <= 33792)
  #pragma unroll
  for (int p = 0; p < 2; ++p){
    __syncthreads();
    if ((wave >> 1) == p){
      #pragma unroll
      for (int s = 0; s < 2; ++s)
        #pragma unroll
        for (int reg = 0; reg < 4; ++reg){
          int rloc = (wave & 1)*32 + s*16 + quad*4 + reg;   // 0..63 within pass
          #pragma unroll
          for (int e = 0; e < 4; ++e){
            Md[rloc*65 + lcol*4 + e] = bd[s][reg][e];
            Mi[rloc*65 + lcol*4 + e] = bi[s][reg][e];
          }
        }
    }
    __syncthreads();
    if (tid < 64){
      float fd[4]; int fi[4];
      #pragma unroll
      for (int e = 0; e < 4; ++e){ fd[e] = FLTMAX; fi[e] = 0; }
      for (int s = 0; s < 64; ++s) upd4(fd, fi, Md[tid*65 + s], Mi[tid*65 + s]);
      int gi = i0 + p*64 + tid;
      #pragma unroll
      for (int e = 0; e < 4; ++e) cand32[(size_t)gi*32 + sl*4 + e] = fi[e];
    }
  }
}

// Rescore the 32 candidates replicating the np reference's fp32 pipeline
// op-for-op: dot = sequential-in-k fp32 FMA chain (OpenBLAS sgemm microkernel),
// d2 = fl32( fl32(sq_i+sq_j) - 2*dot ). Rank by (d2, index) lex.
__global__ __launch_bounds__(64) void rescore_kernel(const float* __restrict__ x,
                                                     const float* __restrict__ sqf,
                                                     const int* __restrict__ cand32,
                                                     int* __restrict__ idx_out,
                                                     int* __restrict__ Bdeg){
  #pragma clang fp contract(off)
  __shared__ float Xi[256];
  __shared__ float Xc[32][260];
  __shared__ float dc[32];
  __shared__ int   jc[32];
  int i = blockIdx.x;
  int t = threadIdx.x;            // 0..63
  ((float4*)Xi)[t] = ((const float4*)(x + (size_t)i * HID))[t];
  if (t < 32) jc[t] = cand32[(size_t)(i << 5) + t];
  __syncthreads();
  for (int r = 0; r < 32; ++r){
    int j = jc[r];
    ((float4*)&Xc[r][0])[t] = ((const float4*)(x + (size_t)j * HID))[t];
  }
  __syncthreads();
  if (t < 32){
    float acc = 0.f;
    for (int k = 0; k < 256; ++k) acc = fmaf(Xi[k], Xc[t][k], acc);
    float t1 = sqf[i] + sqf[jc[t]];
    dc[t] = t1 - 2.0f * acc;
  }
  __syncthreads();
  if (t == 0){
    unsigned taken = 0;
    #pragma unroll
    for (int k = 0; k < 4; ++k){
      float bdv = FLTMAX; int bj = 0x7fffffff, bs = -1;
      for (int s = 0; s < 32; ++s){
        if (taken & (1u << s)) continue;
        float d = dc[s]; int j = jc[s];
        if (d < bdv || (d == bdv && j < bj)){ bdv = d; bj = j; bs = s; }
      }
      taken |= 1u << bs;
      idx_out[i*4 + k] = bj;
      atomicAdd(&Bdeg[bj], 1);
    }
  }
}

// out[i][o] = sum_k A[i][k] * W[o][k]   (A: Mx256 f16, W staged f16, out f16)
__global__ __launch_bounds__(256) void gemm_xw(const _Float16* __restrict__ A,
                                               const _Float16* __restrict__ W,
                                               _Float16* __restrict__ out){
  __shared__ unsigned short Ws[64 * LDSK];
  int tid = threadIdx.x;
  int i0 = (blockIdx.x >> 2) * 64;
  int o0 = (blockIdx.x & 3)  * 64;
  int wave = tid >> 6, lane = tid & 63, quad = lane >> 4, lcol = lane & 15;
  load_tile64(Ws, (const unsigned short*)(W + (size_t)o0 * HID), tid);
  f16x8 a[8];
  const _Float16* arow = A + (size_t)(i0 + wave*16 + lcol) * HID + quad*8;
  #pragma unroll
  for (int ks = 0; ks < 8; ++ks) a[ks] = *(const f16x8*)(arow + ks*32);
  __syncthreads();
  #pragma unroll
  for (int sub = 0; sub < 4; ++sub){
    f32x4 acc = {0.f, 0.f, 0.f, 0.f};
    #pragma unroll
    for (int ks = 0; ks < 8; ++ks){
      f16x8 b = *(const f16x8*)&Ws[(sub*16 + lcol)*LDSK + quad*8 + ks*32];
      acc = __builtin_amdgcn_mfma_f32_16x16x32_f16(a[ks], b, acc, 0, 0, 0);
    }
    #pragma unroll
    for (int reg = 0; reg < 4; ++reg)
      out[(size_t)(i0 + wave*16 + quad*4 + reg)*HID + o0 + sub*16 + lcol] = (_Float16)acc[reg];
  }
}

__global__ __launch_bounds__(256) void prefix_kernel(const int* __restrict__ Bdeg,
                                                     int* __restrict__ off,
                                                     int* __restrict__ cursor){
  __shared__ int psum[256];
  __shared__ int excl[256];
  int t = threadIdx.x;
  int base = t * 64;
  int s = 0;
  for (int k = 0; k < 64; ++k) s += Bdeg[base + k];
  psum[t] = s;
  __syncthreads();
  if (t == 0){ int a = 0; for (int k = 0; k < 256; ++k){ excl[k] = a; a += psum[k]; } }
  __syncthreads();
  int a = excl[t];
  for (int k = 0; k < 64; ++k){ int dv = Bdeg[base + k]; off[base+k] = a; cursor[base+k] = a; a += dv; }
}

__global__ __launch_bounds__(256) void fill_kernel(const int* __restrict__ idx,
                                                   int* __restrict__ cursor,
                                                   int* __restrict__ rev){
  int i = blockIdx.x * 256 + threadIdx.x;
  #pragma unroll
  for (int t = 0; t < 4; ++t){
    int e = idx[i*4 + t];
    int p = atomicAdd(&cursor[e], 1);
    rev[p] = i;
  }
}

// E[e] = mean over contributing nodes of xt[node]  (gather via reverse CSR)
__global__ __launch_bounds__(256) void efeat_kernel(const _Float16* __restrict__ xt,
                                                    const int* __restrict__ off,
                                                    const int* __restrict__ deg,
                                                    const int* __restrict__ rev,
                                                    _Float16* __restrict__ E){
  int e = blockIdx.x, c = threadIdx.x;
  int o = off[e], d = deg[e];
  float s = 0.f;
  for (int k = 0; k < d; ++k) s += (float)xt[(size_t)rev[o + k]*HID + c];
  E[(size_t)e*HID + c] = (_Float16)((d > 0) ? s / (float)d : 0.f);
}

__global__ __launch_bounds__(256) void fin1_kernel(const _Float16* __restrict__ E,
                                                   const int* __restrict__ idx,
                                                   const float* __restrict__ b1,
                                                   const float* __restrict__ pa,
                                                   _Float16* __restrict__ h1){
  int i = blockIdx.x, c = threadIdx.x;
  const int* ip = idx + i*4;
  float s = (float)E[(size_t)ip[0]*HID + c] + (float)E[(size_t)ip[1]*HID + c]
          + (float)E[(size_t)ip[2]*HID + c] + (float)E[(size_t)ip[3]*HID + c];
  float acc = 0.25f * s + b1[c];
  float a = pa[0];
  acc = (acc >= 0.f) ? acc : a * acc;
  h1[(size_t)i*HID + c] = (_Float16)acc;
}

__global__ __launch_bounds__(256) void fin2_kernel(const _Float16* __restrict__ E,
                                                   const int* __restrict__ idx,
                                                   const float* __restrict__ b2,
                                                   const float* __restrict__ x,
                                                   const float* __restrict__ pa,
                                                   float* __restrict__ out){
  int i = blockIdx.x, c = threadIdx.x;
  const int* ip = idx + i*4;
  float s = (float)E[(size_t)ip[0]*HID + c] + (float)E[(size_t)ip[1]*HID + c]
          + (float)E[(size_t)ip[2]*HID + c] + (float)E[(size_t)ip[3]*HID + c];
  float acc = 0.25f * s + b2[c] + x[(size_t)i*HID + c];
  float a = pa[0];
  acc = (acc >= 0.f) ? acc : a * acc;
  out[(size_t)i*HID + c] = acc;
}

extern "C" void kernel_launch(void* const* d_in, const int* in_sizes, int n_in,
                              void* d_out, int out_size, void* d_ws, size_t ws_size,
                              hipStream_t stream){
  (void)in_sizes; (void)n_in; (void)out_size; (void)ws_size;
  const float* x  = (const float*)d_in[0];
  // d_in[1] = edge_index (int32), unused by the math
  const float* W1 = (const float*)d_in[2];
  const float* b1 = (const float*)d_in[3];
  const float* W2 = (const float*)d_in[4];
  const float* b2 = (const float*)d_in[5];
  const float* pa = (const float*)d_in[6];
  float* out = (float*)d_out;

  char* ws = (char*)d_ws;
  float*  sqf    = (float*) (ws + 0);                        //  64 KB
  int*    idx    = (int*)   (ws + 65536);                    // 256 KB
  int*    Bdeg   = (int*)   (ws + 327680);                   //  64 KB
  int*    offE   = (int*)   (ws + 393216);                   //  64 KB
  int*    cursor = (int*)   (ws + 458752);                   //  64 KB
  int*    rev    = (int*)   (ws + 524288);                   // 256 KB
  int*    cand32 = (int*)   (ws + (size_t)(1<<20));          //   2 MB
  _Float16* xh   = (_Float16*)(ws + (size_t)(3<<20));        //   8 MB
  _Float16* W1h  = (_Float16*)(ws + (size_t)(11<<20));       // 128 KB
  _Float16* W2h  = (_Float16*)(ws + (size_t)(11<<20) + 131072);
  _Float16* xt   = (_Float16*)(ws + (size_t)(11<<20) + 262144);            // 8 MB
  _Float16* E    = (_Float16*)(ws + (size_t)(19<<20) + 262144);            // 8 MB
  _Float16* h1   = (_Float16*)(ws + (size_t)(27<<20) + 262144);            // 8 MB

  hipMemsetAsync(Bdeg, 0, NN*sizeof(int), stream);
  cvt_kernel    <<<(NN*HID)/1024, 256, 0, stream>>>(x,  xh);
  cvt_kernel    <<<(HID*HID)/1024, 256, 0, stream>>>(W1, W1h);
  cvt_kernel    <<<(HID*HID)/1024, 256, 0, stream>>>(W2, W2h);
  sumsq_np_kernel<<<NN/16, 256, 0, stream>>>(x, sqf);
  knn_kernel    <<<(NN/128)*NSLICE, 256, 0, stream>>>(xh, sqf, cand32);
  rescore_kernel<<<NN,      64, 0, stream>>>(x, sqf, cand32, idx, Bdeg);
  prefix_kernel <<<1,      256, 0, stream>>>(Bdeg, offE, cursor);
  fill_kernel   <<<NN/256, 256, 0, stream>>>(idx, cursor, rev);

  gemm_xw       <<<(NN/64)*4, 256, 0, stream>>>(xh, W1h, xt);
  efeat_kernel  <<<NN,        256, 0, stream>>>(xt, offE, Bdeg, rev, E);
  fin1_kernel   <<<NN,        256, 0, stream>>>(E, idx, b1, pa, h1);

  gemm_xw       <<<(NN/64)*4, 256, 0, stream>>>(h1, W2h, xt);
  efeat_kernel  <<<NN,        256, 0, stream>>>(xt, offE, Bdeg, rev, E);
  fin2_kernel   <<<NN,        256, 0, stream>>>(E, idx, b2, x, pa, out);
}

// Round 7
// 863.463 us; speedup vs baseline: 1.3987x; 1.3987x over previous
//
#include <hip/hip_runtime.h>
#include <stdint.h>

#define NN   16384
#define HID  256
#define LDSK 264            // padded LDS row stride in f16 elems (16B-aligned)
#define NSLICE 8
#define JSL  (NN/NSLICE)    // 2048 j's per slice
#define FLTMAX 3.402823466e38f

typedef __attribute__((ext_vector_type(8))) _Float16 f16x8;
typedef __attribute__((ext_vector_type(4))) _Float16 f16x4;
typedef __attribute__((ext_vector_type(4))) float f32x4;

// ---- fp32 -> fp16 converter ----
__global__ __launch_bounds__(256) void cvt_kernel(const float* __restrict__ in,
                                                  _Float16* __restrict__ out){
  int t = blockIdx.x * 256 + threadIdx.x;
  float4 v = ((const float4*)in)[t];
  f16x4 h; h.x = (_Float16)v.x; h.y = (_Float16)v.y; h.z = (_Float16)v.z; h.w = (_Float16)v.w;
  ((f16x4*)out)[t] = h;
}

// ---- row sum-of-squares, bit-replicating numpy fp32 pairwise summation ----
// numpy n=256: two 128-halves; each: 8 stride-8 accumulators (sequential adds),
// combine ((r0+r1)+(r2+r3))+((r4+r5)+(r6+r7)); total = h0 + h1.
// m = xs*xs rounds separately from the add (contract off, NO fma here).
__global__ __launch_bounds__(256) void sumsq_np_kernel(const float* __restrict__ x,
                                                       float* __restrict__ sqf){
  #pragma clang fp contract(off)
  int lane = threadIdx.x & 63;
  int rw   = lane >> 4;                 // row within wave (4 rows/wave)
  int h    = (lane >> 3) & 1;           // half
  int j    = lane & 7;                  // accumulator index
  int row  = (blockIdx.x * 4 + (threadIdx.x >> 6)) * 4 + rw;
  const float* p = x + (size_t)row * HID + h*128 + j;
  float v0 = p[0];
  float r  = v0 * v0;
  #pragma unroll
  for (int i = 1; i < 16; ++i){ float v = p[i*8]; float m = v * v; r = r + m; }
  float t1 = r  + __shfl_xor(r,  1);
  float t2 = t1 + __shfl_xor(t1, 2);
  float t3 = t2 + __shfl_xor(t2, 4);
  float tot = t3 + __shfl_xor(t3, 8);   // h0 + h1 on h==0 lanes
  if (h == 0 && j == 0) sqf[row] = tot;
}

// stage 64x256 f16 tile into LDS with padded stride (256 threads)
__device__ __forceinline__ void load_tile64(unsigned short* dst, const unsigned short* src, int tid){
  const uint4* s = (const uint4*)src;
  #pragma unroll
  for (int r = 0; r < 8; ++r){
    int fl  = tid + (r << 8);
    int row = fl >> 5;
    int c   = fl & 31;
    *(uint4*)&dst[row*LDSK + (c << 3)] = s[fl];
  }
}

// running top-4 (smallest) insert, strict <
__device__ __forceinline__ void upd4(float (&bd)[4], int (&bi)[4], float d, int j){
  if (d < bd[3]){
    if      (d < bd[0]){ bd[3]=bd[2];bi[3]=bi[2]; bd[2]=bd[1];bi[2]=bi[1]; bd[1]=bd[0];bi[1]=bi[0]; bd[0]=d; bi[0]=j; }
    else if (d < bd[1]){ bd[3]=bd[2];bi[3]=bi[2]; bd[2]=bd[1];bi[2]=bi[1]; bd[1]=d; bi[1]=j; }
    else if (d < bd[2]){ bd[3]=bd[2];bi[3]=bi[2]; bd[2]=d; bi[2]=j; }
    else               { bd[3]=d; bi[3]=j; }
  }
}

// fp16 MFMA Gram with SWAPPED operand roles: first operand = Xj tile (LDS,
// streamed), second = stationary i-rows (registers). C: row = j-local
// (quad*4+reg), col = i-local (lcol) -> each lane owns ONE i, so the scan
// state is just bd[4]/bi[4] (8 VGPRs) -- no spills. i-tile 64/block, j
// sliced 8-way; 4 candidates per (i, slice) -> 32/row, rescored exactly later.
__global__ __launch_bounds__(256, 4) void knn_kernel(const _Float16* __restrict__ xh,
                                                     const float* __restrict__ sqf,
                                                     int* __restrict__ cand32){
  __shared__ unsigned short Xj[64 * LDSK];   // 33792 B staging; aliased as merge buffer
  __shared__ float sqj[64];

  int tid  = threadIdx.x;
  int sl   = blockIdx.x & (NSLICE-1);
  int i0   = (blockIdx.x >> 3) * 64;
  int jb0  = sl * JSL;
  int wave = tid >> 6, lane = tid & 63, quad = lane >> 4, lcol = lane & 15;

  // stationary operand: this lane's i-row fragments (r=lcol, k=quad*8+ks*32)
  f16x8 bfr[8];
  {
    const _Float16* br = xh + (size_t)(i0 + wave*16 + lcol) * HID + quad*8;
    #pragma unroll
    for (int ks = 0; ks < 8; ++ks) bfr[ks] = *(const f16x8*)(br + ks*32);
  }
  int gi = i0 + wave*16 + lcol;          // the i this lane ranks neighbors for

  float bd[4] = {FLTMAX,FLTMAX,FLTMAX,FLTMAX};
  int   bi[4] = {0,0,0,0};

  for (int it = 0; it < JSL; it += 64){
    int jb = jb0 + it;
    __syncthreads();
    load_tile64(Xj, (const unsigned short*)(xh + (size_t)jb * HID), tid);
    if (tid < 64) sqj[tid] = sqf[jb + tid];
    __syncthreads();

    #pragma unroll
    for (int sub = 0; sub < 4; ++sub){
      f32x4 acc = {0.f,0.f,0.f,0.f};
      #pragma unroll
      for (int ks = 0; ks < 8; ++ks){
        f16x8 a = *(const f16x8*)&Xj[(sub*16 + lcol)*LDSK + quad*8 + ks*32];
        acc = __builtin_amdgcn_mfma_f32_16x16x32_f16(a, bfr[ks], acc, 0, 0, 0);
      }
      // C: row = j-local = quad*4+reg, col = i-local = lcol
      float4 sj4 = *(const float4*)&sqj[sub*16 + quad*4];
      int jbase = jb + sub*16 + quad*4;
      #pragma unroll
      for (int reg = 0; reg < 4; ++reg){
        int gj = jbase + reg;
        float v = (gj == gi) ? FLTMAX : fmaf(-2.f, acc[reg], (&sj4.x)[reg]);
        upd4(bd, bi, v, gj);
      }
    }
  }

  // merge across the 4 quads per i: 16 candidates -> top-4 (LDS aliased on Xj)
  __syncthreads();
  float* Md = (float*)Xj;                // 64 x 17 floats  (4.4 KB)
  int*   Mi = (int*)Xj + 64*17;          // 64 x 17 ints    (4.4 KB)
  {
    int base = (wave*16 + lcol)*17 + quad*4;
    #pragma unroll
    for (int e = 0; e < 4; ++e){ Md[base+e] = bd[e]; Mi[base+e] = bi[e]; }
  }
  __syncthreads();
  if (tid < 64){
    float fd[4]; int fi[4];
    #pragma unroll
    for (int e = 0; e < 4; ++e){ fd[e] = FLTMAX; fi[e] = 0; }
    #pragma unroll
    for (int s = 0; s < 16; ++s) upd4(fd, fi, Md[tid*17 + s], Mi[tid*17 + s]);
    int g = i0 + tid;
    #pragma unroll
    for (int e = 0; e < 4; ++e) cand32[(size_t)g*32 + sl*4 + e] = fi[e];
  }
}

// Rescore the 32 candidates replicating the np reference's fp32 pipeline
// op-for-op: dot = sequential-in-k fp32 FMA chain (OpenBLAS sgemm microkernel),
// d2 = fl32( fl32(sq_i+sq_j) - 2*dot ). Rank by (d2, index) lex.
__global__ __launch_bounds__(64) void rescore_kernel(const float* __restrict__ x,
                                                     const float* __restrict__ sqf,
                                                     const int* __restrict__ cand32,
                                                     int* __restrict__ idx_out,
                                                     int* __restrict__ Bdeg){
  #pragma clang fp contract(off)
  __shared__ float Xi[256];
  __shared__ float Xc[32][260];
  __shared__ float dc[32];
  __shared__ int   jc[32];
  int i = blockIdx.x;
  int t = threadIdx.x;            // 0..63
  ((float4*)Xi)[t] = ((const float4*)(x + (size_t)i * HID))[t];
  if (t < 32) jc[t] = cand32[(size_t)(i << 5) + t];
  __syncthreads();
  for (int r = 0; r < 32; ++r){
    int j = jc[r];
    ((float4*)&Xc[r][0])[t] = ((const float4*)(x + (size_t)j * HID))[t];
  }
  __syncthreads();
  if (t < 32){
    float acc = 0.f;
    for (int k = 0; k < 256; ++k) acc = fmaf(Xi[k], Xc[t][k], acc);
    float t1 = sqf[i] + sqf[jc[t]];
    dc[t] = t1 - 2.0f * acc;
  }
  __syncthreads();
  if (t == 0){
    unsigned taken = 0;
    #pragma unroll
    for (int k = 0; k < 4; ++k){
      float bdv = FLTMAX; int bj = 0x7fffffff, bs = -1;
      for (int s = 0; s < 32; ++s){
        if (taken & (1u << s)) continue;
        float d = dc[s]; int j = jc[s];
        if (d < bdv || (d == bdv && j < bj)){ bdv = d; bj = j; bs = s; }
      }
      taken |= 1u << bs;
      idx_out[i*4 + k] = bj;
      atomicAdd(&Bdeg[bj], 1);
    }
  }
}

// out[i][o] = sum_k A[i][k] * W[o][k]   (A: Mx256 f16, W staged f16, out f16)
__global__ __launch_bounds__(256) void gemm_xw(const _Float16* __restrict__ A,
                                               const _Float16* __restrict__ W,
                                               _Float16* __restrict__ out){
  __shared__ unsigned short Ws[64 * LDSK];
  int tid = threadIdx.x;
  int i0 = (blockIdx.x >> 2) * 64;
  int o0 = (blockIdx.x & 3)  * 64;
  int wave = tid >> 6, lane = tid & 63, quad = lane >> 4, lcol = lane & 15;
  load_tile64(Ws, (const unsigned short*)(W + (size_t)o0 * HID), tid);
  f16x8 a[8];
  const _Float16* arow = A + (size_t)(i0 + wave*16 + lcol) * HID + quad*8;
  #pragma unroll
  for (int ks = 0; ks < 8; ++ks) a[ks] = *(const f16x8*)(arow + ks*32);
  __syncthreads();
  #pragma unroll
  for (int sub = 0; sub < 4; ++sub){
    f32x4 acc = {0.f, 0.f, 0.f, 0.f};
    #pragma unroll
    for (int ks = 0; ks < 8; ++ks){
      f16x8 b = *(const f16x8*)&Ws[(sub*16 + lcol)*LDSK + quad*8 + ks*32];
      acc = __builtin_amdgcn_mfma_f32_16x16x32_f16(a[ks], b, acc, 0, 0, 0);
    }
    #pragma unroll
    for (int reg = 0; reg < 4; ++reg)
      out[(size_t)(i0 + wave*16 + quad*4 + reg)*HID + o0 + sub*16 + lcol] = (_Float16)acc[reg];
  }
}

__global__ __launch_bounds__(256) void prefix_kernel(const int* __restrict__ Bdeg,
                                                     int* __restrict__ off,
                                                     int* __restrict__ cursor){
  __shared__ int psum[256];
  __shared__ int excl[256];
  int t = threadIdx.x;
  int base = t * 64;
  int s = 0;
  for (int k = 0; k < 64; ++k) s += Bdeg[base + k];
  psum[t] = s;
  __syncthreads();
  if (t == 0){ int a = 0; for (int k = 0; k < 256; ++k){ excl[k] = a; a += psum[k]; } }
  __syncthreads();
  int a = excl[t];
  for (int k = 0; k < 64; ++k){ int dv = Bdeg[base + k]; off[base+k] = a; cursor[base+k] = a; a += dv; }
}

__global__ __launch_bounds__(256) void fill_kernel(const int* __restrict__ idx,
                                                   int* __restrict__ cursor,
                                                   int* __restrict__ rev){
  int i = blockIdx.x * 256 + threadIdx.x;
  #pragma unroll
  for (int t = 0; t < 4; ++t){
    int e = idx[i*4 + t];
    int p = atomicAdd(&cursor[e], 1);
    rev[p] = i;
  }
}

// E[e] = mean over contributing nodes of xt[node]  (gather via reverse CSR)
__global__ __launch_bounds__(256) void efeat_kernel(const _Float16* __restrict__ xt,
                                                    const int* __restrict__ off,
                                                    const int* __restrict__ deg,
                                                    const int* __restrict__ rev,
                                                    _Float16* __restrict__ E){
  int e = blockIdx.x, c = threadIdx.x;
  int o = off[e], d = deg[e];
  float s = 0.f;
  for (int k = 0; k < d; ++k) s += (float)xt[(size_t)rev[o + k]*HID + c];
  E[(size_t)e*HID + c] = (_Float16)((d > 0) ? s / (float)d : 0.f);
}

__global__ __launch_bounds__(256) void fin1_kernel(const _Float16* __restrict__ E,
                                                   const int* __restrict__ idx,
                                                   const float* __restrict__ b1,
                                                   const float* __restrict__ pa,
                                                   _Float16* __restrict__ h1){
  int i = blockIdx.x, c = threadIdx.x;
  const int* ip = idx + i*4;
  float s = (float)E[(size_t)ip[0]*HID + c] + (float)E[(size_t)ip[1]*HID + c]
          + (float)E[(size_t)ip[2]*HID + c] + (float)E[(size_t)ip[3]*HID + c];
  float acc = 0.25f * s + b1[c];
  float a = pa[0];
  acc = (acc >= 0.f) ? acc : a * acc;
  h1[(size_t)i*HID + c] = (_Float16)acc;
}

__global__ __launch_bounds__(256) void fin2_kernel(const _Float16* __restrict__ E,
                                                   const int* __restrict__ idx,
                                                   const float* __restrict__ b2,
                                                   const float* __restrict__ x,
                                                   const float* __restrict__ pa,
                                                   float* __restrict__ out){
  int i = blockIdx.x, c = threadIdx.x;
  const int* ip = idx + i*4;
  float s = (float)E[(size_t)ip[0]*HID + c] + (float)E[(size_t)ip[1]*HID + c]
          + (float)E[(size_t)ip[2]*HID + c] + (float)E[(size_t)ip[3]*HID + c];
  float acc = 0.25f * s + b2[c] + x[(size_t)i*HID + c];
  float a = pa[0];
  acc = (acc >= 0.f) ? acc : a * acc;
  out[(size_t)i*HID + c] = acc;
}

extern "C" void kernel_launch(void* const* d_in, const int* in_sizes, int n_in,
                              void* d_out, int out_size, void* d_ws, size_t ws_size,
                              hipStream_t stream){
  (void)in_sizes; (void)n_in; (void)out_size; (void)ws_size;
  const float* x  = (const float*)d_in[0];
  // d_in[1] = edge_index (int32), unused by the math
  const float* W1 = (const float*)d_in[2];
  const float* b1 = (const float*)d_in[3];
  const float* W2 = (const float*)d_in[4];
  const float* b2 = (const float*)d_in[5];
  const float* pa = (const float*)d_in[6];
  float* out = (float*)d_out;

  char* ws = (char*)d_ws;
  float*  sqf    = (float*) (ws + 0);                        //  64 KB
  int*    idx    = (int*)   (ws + 65536);                    // 256 KB
  int*    Bdeg   = (int*)   (ws + 327680);                   //  64 KB
  int*    offE   = (int*)   (ws + 393216);                   //  64 KB
  int*    cursor = (int*)   (ws + 458752);                   //  64 KB
  int*    rev    = (int*)   (ws + 524288);                   // 256 KB
  int*    cand32 = (int*)   (ws + (size_t)(1<<20));          //   2 MB
  _Float16* xh   = (_Float16*)(ws + (size_t)(3<<20));        //   8 MB
  _Float16* W1h  = (_Float16*)(ws + (size_t)(11<<20));       // 128 KB
  _Float16* W2h  = (_Float16*)(ws + (size_t)(11<<20) + 131072);
  _Float16* xt   = (_Float16*)(ws + (size_t)(11<<20) + 262144);            // 8 MB
  _Float16* E    = (_Float16*)(ws + (size_t)(19<<20) + 262144);            // 8 MB
  _Float16* h1   = (_Float16*)(ws + (size_t)(27<<20) + 262144);            // 8 MB

  hipMemsetAsync(Bdeg, 0, NN*sizeof(int), stream);
  cvt_kernel    <<<(NN*HID)/1024, 256, 0, stream>>>(x,  xh);
  cvt_kernel    <<<(HID*HID)/1024, 256, 0, stream>>>(W1, W1h);
  cvt_kernel    <<<(HID*HID)/1024, 256, 0, stream>>>(W2, W2h);
  sumsq_np_kernel<<<NN/16, 256, 0, stream>>>(x, sqf);
  knn_kernel    <<<(NN/64)*NSLICE, 256, 0, stream>>>(xh, sqf, cand32);
  rescore_kernel<<<NN,      64, 0, stream>>>(x, sqf, cand32, idx, Bdeg);
  prefix_kernel <<<1,      256, 0, stream>>>(Bdeg, offE, cursor);
  fill_kernel   <<<NN/256, 256, 0, stream>>>(idx, cursor, rev);

  gemm_xw       <<<(NN/64)*4, 256, 0, stream>>>(xh, W1h, xt);
  efeat_kernel  <<<NN,        256, 0, stream>>>(xt, offE, Bdeg, rev, E);
  fin1_kernel   <<<NN,        256, 0, stream>>>(E, idx, b1, pa, h1);

  gemm_xw       <<<(NN/64)*4, 256, 0, stream>>>(h1, W2h, xt);
  efeat_kernel  <<<NN,        256, 0, stream>>>(xt, offE, Bdeg, rev, E);
  fin2_kernel   <<<NN,        256, 0, stream>>>(E, idx, b2, x, pa, out);
}

// Round 8
// 836.110 us; speedup vs baseline: 1.4445x; 1.0327x over previous
//
#include <hip/hip_runtime.h>
#include <stdint.h>

#define NN   16384
#define HID  256
#define LDSK 264            // padded LDS row stride in f16 elems (16B-aligned)
#define NSLICE 8
#define JSL  (NN/NSLICE)    // 2048 j's per slice
#define FLTMAX 3.402823466e38f

typedef __attribute__((ext_vector_type(8))) _Float16 f16x8;
typedef __attribute__((ext_vector_type(4))) _Float16 f16x4;
typedef __attribute__((ext_vector_type(4))) float f32x4;

// ---- fused fp32 -> fp16 converter for x, W1, W2 (one launch) ----
#define NXG (NN*HID/4)
#define NWG (HID*HID/4)
__global__ __launch_bounds__(256) void cvt_all_kernel(const float* __restrict__ x,
                                                      const float* __restrict__ W1,
                                                      const float* __restrict__ W2,
                                                      _Float16* __restrict__ xh,
                                                      _Float16* __restrict__ W1h,
                                                      _Float16* __restrict__ W2h){
  int g = blockIdx.x * 256 + threadIdx.x;
  const float* src; _Float16* dst; int o;
  if (g < NXG)            { src = x;  dst = xh;  o = g; }
  else if (g < NXG + NWG) { src = W1; dst = W1h; o = g - NXG; }
  else                    { src = W2; dst = W2h; o = g - NXG - NWG; }
  float4 v = ((const float4*)src)[o];
  f16x4 h; h.x = (_Float16)v.x; h.y = (_Float16)v.y; h.z = (_Float16)v.z; h.w = (_Float16)v.w;
  ((f16x4*)dst)[o] = h;
}

// ---- row sum-of-squares, bit-replicating numpy fp32 pairwise summation ----
__global__ __launch_bounds__(256) void sumsq_np_kernel(const float* __restrict__ x,
                                                       float* __restrict__ sqf){
  #pragma clang fp contract(off)
  int lane = threadIdx.x & 63;
  int rw   = lane >> 4;
  int h    = (lane >> 3) & 1;
  int j    = lane & 7;
  int row  = (blockIdx.x * 4 + (threadIdx.x >> 6)) * 4 + rw;
  const float* p = x + (size_t)row * HID + h*128 + j;
  float v0 = p[0];
  float r  = v0 * v0;
  #pragma unroll
  for (int i = 1; i < 16; ++i){ float v = p[i*8]; float m = v * v; r = r + m; }
  float t1 = r  + __shfl_xor(r,  1);
  float t2 = t1 + __shfl_xor(t1, 2);
  float t3 = t2 + __shfl_xor(t2, 4);
  float tot = t3 + __shfl_xor(t3, 8);
  if (h == 0 && j == 0) sqf[row] = tot;
}

// stage 64x256 f16 tile into LDS with padded stride (256 threads)
__device__ __forceinline__ void load_tile64(unsigned short* dst, const unsigned short* src, int tid){
  const uint4* s = (const uint4*)src;
  #pragma unroll
  for (int r = 0; r < 8; ++r){
    int fl  = tid + (r << 8);
    int row = fl >> 5;
    int c   = fl & 31;
    *(uint4*)&dst[row*LDSK + (c << 3)] = s[fl];
  }
}

// running top-4 (smallest) insert, strict <
__device__ __forceinline__ void upd4(float (&bd)[4], int (&bi)[4], float d, int j){
  if (d < bd[3]){
    if      (d < bd[0]){ bd[3]=bd[2];bi[3]=bi[2]; bd[2]=bd[1];bi[2]=bi[1]; bd[1]=bd[0];bi[1]=bi[0]; bd[0]=d; bi[0]=j; }
    else if (d < bd[1]){ bd[3]=bd[2];bi[3]=bi[2]; bd[2]=bd[1];bi[2]=bi[1]; bd[1]=d; bi[1]=j; }
    else if (d < bd[2]){ bd[3]=bd[2];bi[3]=bi[2]; bd[2]=d; bi[2]=j; }
    else               { bd[3]=d; bi[3]=j; }
  }
}

// fp16 MFMA Gram, swapped operand roles (streamed j-tile = first operand from
// LDS, stationary i-rows = second, C col = i = lcol). TWO stationary i-sets
// per wave: each LDS a-fragment feeds 2 MFMAs -> LDS read traffic halves and
// the two interleaved acc chains double MFMA ILP. i-tile 128/block, j sliced
// 8-way; 4 candidates per (i, slice) -> 32/row, rescored exactly later.
__global__ __launch_bounds__(256, 4) void knn_kernel(const _Float16* __restrict__ xh,
                                                     const float* __restrict__ sqf,
                                                     int* __restrict__ cand32){
  __shared__ unsigned short Xj[64 * LDSK];   // 33792 B staging; aliased as merge buffer
  __shared__ float sqj[64];

  int tid  = threadIdx.x;
  int sl   = blockIdx.x & (NSLICE-1);
  int i0   = (blockIdx.x >> 3) * 128;
  int jb0  = sl * JSL;
  int wave = tid >> 6, lane = tid & 63, quad = lane >> 4, lcol = lane & 15;

  // stationary operands: rows i0 + {0,64} + wave*16 + lcol
  f16x8 bfr0[8], bfr1[8];
  {
    const _Float16* br0 = xh + (size_t)(i0 +      wave*16 + lcol) * HID + quad*8;
    const _Float16* br1 = xh + (size_t)(i0 + 64 + wave*16 + lcol) * HID + quad*8;
    #pragma unroll
    for (int ks = 0; ks < 8; ++ks){ bfr0[ks] = *(const f16x8*)(br0 + ks*32); bfr1[ks] = *(const f16x8*)(br1 + ks*32); }
  }
  int gi0 = i0 + wave*16 + lcol;
  int gi1 = gi0 + 64;

  float bd0[4] = {FLTMAX,FLTMAX,FLTMAX,FLTMAX}; int bi0[4] = {0,0,0,0};
  float bd1[4] = {FLTMAX,FLTMAX,FLTMAX,FLTMAX}; int bi1[4] = {0,0,0,0};

  for (int it = 0; it < JSL; it += 64){
    int jb = jb0 + it;
    __syncthreads();
    load_tile64(Xj, (const unsigned short*)(xh + (size_t)jb * HID), tid);
    if (tid < 64) sqj[tid] = sqf[jb + tid];
    __syncthreads();

    #pragma unroll
    for (int sub = 0; sub < 4; ++sub){
      f32x4 acc0 = {0.f,0.f,0.f,0.f}, acc1 = {0.f,0.f,0.f,0.f};
      #pragma unroll
      for (int ks = 0; ks < 8; ++ks){
        f16x8 a = *(const f16x8*)&Xj[(sub*16 + lcol)*LDSK + quad*8 + ks*32];
        acc0 = __builtin_amdgcn_mfma_f32_16x16x32_f16(a, bfr0[ks], acc0, 0, 0, 0);
        acc1 = __builtin_amdgcn_mfma_f32_16x16x32_f16(a, bfr1[ks], acc1, 0, 0, 0);
      }
      // C: row = j-local = quad*4+reg, col = i-local = lcol
      float4 sj4 = *(const float4*)&sqj[sub*16 + quad*4];
      int jbase = jb + sub*16 + quad*4;
      #pragma unroll
      for (int reg = 0; reg < 4; ++reg){
        int gj = jbase + reg;
        float sj = (&sj4.x)[reg];
        float v0 = (gj == gi0) ? FLTMAX : fmaf(-2.f, acc0[reg], sj);
        float v1 = (gj == gi1) ? FLTMAX : fmaf(-2.f, acc1[reg], sj);
        upd4(bd0, bi0, v0, gj);
        upd4(bd1, bi1, v1, gj);
      }
    }
  }

  // merge across the 4 quads per i: 16 candidates -> top-4 (LDS aliased on Xj)
  __syncthreads();
  float* Md = (float*)Xj;                // 128 x 17 floats (8.7 KB)
  int*   Mi = (int*)Xj + 128*17;         // 128 x 17 ints   (8.7 KB)
  {
    int r0 = (wave*16 + lcol)*17 + quad*4;
    int r1 = (64 + wave*16 + lcol)*17 + quad*4;
    #pragma unroll
    for (int e = 0; e < 4; ++e){
      Md[r0+e] = bd0[e]; Mi[r0+e] = bi0[e];
      Md[r1+e] = bd1[e]; Mi[r1+e] = bi1[e];
    }
  }
  __syncthreads();
  if (tid < 128){
    float fd[4]; int fi[4];
    #pragma unroll
    for (int e = 0; e < 4; ++e){ fd[e] = FLTMAX; fi[e] = 0; }
    #pragma unroll
    for (int s = 0; s < 16; ++s) upd4(fd, fi, Md[tid*17 + s], Mi[tid*17 + s]);
    int g = i0 + tid;
    #pragma unroll
    for (int e = 0; e < 4; ++e) cand32[(size_t)g*32 + sl*4 + e] = fi[e];
  }
}

// Rescore the 32 candidates replicating the np reference's fp32 pipeline
// op-for-op: dot = sequential-in-k fp32 FMA chain (OpenBLAS sgemm microkernel),
// d2 = fl32( fl32(sq_i+sq_j) - 2*dot ). Rank by (d2, index) lex.
// 256 threads: parallel staging; 32 chains spread as 8 lanes x 4 waves.
__global__ __launch_bounds__(256) void rescore_kernel(const float* __restrict__ x,
                                                      const float* __restrict__ sqf,
                                                      const int* __restrict__ cand32,
                                                      int* __restrict__ idx_out,
                                                      int* __restrict__ Bdeg){
  #pragma clang fp contract(off)
  __shared__ float Xi[256];
  __shared__ float Xc[32][260];
  __shared__ float dc[32];
  __shared__ int   jc[32];
  int i = blockIdx.x;
  int tid = threadIdx.x;
  if (tid < 64) ((float4*)Xi)[tid] = ((const float4*)(x + (size_t)i * HID))[tid];
  if (tid < 32) jc[tid] = cand32[(size_t)(i << 5) + tid];
  __syncthreads();
  {
    int r = tid >> 3, cl = tid & 7;
    const float4* src = (const float4*)(x + (size_t)jc[r] * HID);
    float4* dstr = (float4*)&Xc[r][0];
    #pragma unroll
    for (int k = 0; k < 8; ++k) dstr[cl + 8*k] = src[cl + 8*k];
  }
  __syncthreads();
  {
    int w = tid >> 6, l = tid & 63;
    if (l < 8){
      int c = w*8 + l;
      float acc = 0.f;
      for (int k = 0; k < 256; ++k) acc = fmaf(Xi[k], Xc[c][k], acc);
      float t1   = sqf[i] + sqf[jc[c]];
      float twod = 2.0f * acc;
      dc[c] = t1 - twod;
    }
  }
  __syncthreads();
  if (tid == 0){
    unsigned taken = 0;
    #pragma unroll
    for (int k = 0; k < 4; ++k){
      float bdv = FLTMAX; int bj = 0x7fffffff, bs = -1;
      for (int s = 0; s < 32; ++s){
        if (taken & (1u << s)) continue;
        float d = dc[s]; int j = jc[s];
        if (d < bdv || (d == bdv && j < bj)){ bdv = d; bj = j; bs = s; }
      }
      taken |= 1u << bs;
      idx_out[i*4 + k] = bj;
      atomicAdd(&Bdeg[bj], 1);
    }
  }
}

// out[i][o] = sum_k A[i][k] * W[o][k]   (A: Mx256 f16, W staged f16, out f16)
__global__ __launch_bounds__(256) void gemm_xw(const _Float16* __restrict__ A,
                                               const _Float16* __restrict__ W,
                                               _Float16* __restrict__ out){
  __shared__ unsigned short Ws[64 * LDSK];
  int tid = threadIdx.x;
  int i0 = (blockIdx.x >> 2) * 64;
  int o0 = (blockIdx.x & 3)  * 64;
  int wave = tid >> 6, lane = tid & 63, quad = lane >> 4, lcol = lane & 15;
  load_tile64(Ws, (const unsigned short*)(W + (size_t)o0 * HID), tid);
  f16x8 a[8];
  const _Float16* arow = A + (size_t)(i0 + wave*16 + lcol) * HID + quad*8;
  #pragma unroll
  for (int ks = 0; ks < 8; ++ks) a[ks] = *(const f16x8*)(arow + ks*32);
  __syncthreads();
  #pragma unroll
  for (int sub = 0; sub < 4; ++sub){
    f32x4 acc = {0.f, 0.f, 0.f, 0.f};
    #pragma unroll
    for (int ks = 0; ks < 8; ++ks){
      f16x8 b = *(const f16x8*)&Ws[(sub*16 + lcol)*LDSK + quad*8 + ks*32];
      acc = __builtin_amdgcn_mfma_f32_16x16x32_f16(a[ks], b, acc, 0, 0, 0);
    }
    #pragma unroll
    for (int reg = 0; reg < 4; ++reg)
      out[(size_t)(i0 + wave*16 + quad*4 + reg)*HID + o0 + sub*16 + lcol] = (_Float16)acc[reg];
  }
}

__global__ __launch_bounds__(256) void prefix_kernel(const int* __restrict__ Bdeg,
                                                     int* __restrict__ off,
                                                     int* __restrict__ cursor){
  __shared__ int psum[256];
  __shared__ int excl[256];
  int t = threadIdx.x;
  int base = t * 64;
  int s = 0;
  for (int k = 0; k < 64; ++k) s += Bdeg[base + k];
  psum[t] = s;
  __syncthreads();
  if (t == 0){ int a = 0; for (int k = 0; k < 256; ++k){ excl[k] = a; a += psum[k]; } }
  __syncthreads();
  int a = excl[t];
  for (int k = 0; k < 64; ++k){ int dv = Bdeg[base + k]; off[base+k] = a; cursor[base+k] = a; a += dv; }
}

__global__ __launch_bounds__(256) void fill_kernel(const int* __restrict__ idx,
                                                   int* __restrict__ cursor,
                                                   int* __restrict__ rev){
  int i = blockIdx.x * 256 + threadIdx.x;
  #pragma unroll
  for (int t = 0; t < 4; ++t){
    int e = idx[i*4 + t];
    int p = atomicAdd(&cursor[e], 1);
    rev[p] = i;
  }
}

// E[e] = mean over contributing nodes of xt[node]  (gather via reverse CSR)
__global__ __launch_bounds__(256) void efeat_kernel(const _Float16* __restrict__ xt,
                                                    const int* __restrict__ off,
                                                    const int* __restrict__ deg,
                                                    const int* __restrict__ rev,
                                                    _Float16* __restrict__ E){
  int e = blockIdx.x, c = threadIdx.x;
  int o = off[e], d = deg[e];
  float s = 0.f;
  for (int k = 0; k < d; ++k) s += (float)xt[(size_t)rev[o + k]*HID + c];
  E[(size_t)e*HID + c] = (_Float16)((d > 0) ? s / (float)d : 0.f);
}

__global__ __launch_bounds__(256) void fin1_kernel(const _Float16* __restrict__ E,
                                                   const int* __restrict__ idx,
                                                   const float* __restrict__ b1,
                                                   const float* __restrict__ pa,
                                                   _Float16* __restrict__ h1){
  int i = blockIdx.x, c = threadIdx.x;
  const int* ip = idx + i*4;
  float s = (float)E[(size_t)ip[0]*HID + c] + (float)E[(size_t)ip[1]*HID + c]
          + (float)E[(size_t)ip[2]*HID + c] + (float)E[(size_t)ip[3]*HID + c];
  float acc = 0.25f * s + b1[c];
  float a = pa[0];
  acc = (acc >= 0.f) ? acc : a * acc;
  h1[(size_t)i*HID + c] = (_Float16)acc;
}

__global__ __launch_bounds__(256) void fin2_kernel(const _Float16* __restrict__ E,
                                                   const int* __restrict__ idx,
                                                   const float* __restrict__ b2,
                                                   const float* __restrict__ x,
                                                   const float* __restrict__ pa,
                                                   float* __restrict__ out){
  int i = blockIdx.x, c = threadIdx.x;
  const int* ip = idx + i*4;
  float s = (float)E[(size_t)ip[0]*HID + c] + (float)E[(size_t)ip[1]*HID + c]
          + (float)E[(size_t)ip[2]*HID + c] + (float)E[(size_t)ip[3]*HID + c];
  float acc = 0.25f * s + b2[c] + x[(size_t)i*HID + c];
  float a = pa[0];
  acc = (acc >= 0.f) ? acc : a * acc;
  out[(size_t)i*HID + c] = acc;
}

extern "C" void kernel_launch(void* const* d_in, const int* in_sizes, int n_in,
                              void* d_out, int out_size, void* d_ws, size_t ws_size,
                              hipStream_t stream){
  (void)in_sizes; (void)n_in; (void)out_size; (void)ws_size;
  const float* x  = (const float*)d_in[0];
  // d_in[1] = edge_index (int32), unused by the math
  const float* W1 = (const float*)d_in[2];
  const float* b1 = (const float*)d_in[3];
  const float* W2 = (const float*)d_in[4];
  const float* b2 = (const float*)d_in[5];
  const float* pa = (const float*)d_in[6];
  float* out = (float*)d_out;

  char* ws = (char*)d_ws;
  float*  sqf    = (float*) (ws + 0);                        //  64 KB
  int*    idx    = (int*)   (ws + 65536);                    // 256 KB
  int*    Bdeg   = (int*)   (ws + 327680);                   //  64 KB
  int*    offE   = (int*)   (ws + 393216);                   //  64 KB
  int*    cursor = (int*)   (ws + 458752);                   //  64 KB
  int*    rev    = (int*)   (ws + 524288);                   // 256 KB
  int*    cand32 = (int*)   (ws + (size_t)(1<<20));          //   2 MB
  _Float16* xh   = (_Float16*)(ws + (size_t)(3<<20));        //   8 MB
  _Float16* W1h  = (_Float16*)(ws + (size_t)(11<<20));       // 128 KB
  _Float16* W2h  = (_Float16*)(ws + (size_t)(11<<20) + 131072);
  _Float16* xt   = (_Float16*)(ws + (size_t)(11<<20) + 262144);            // 8 MB
  _Float16* E    = (_Float16*)(ws + (size_t)(19<<20) + 262144);            // 8 MB
  _Float16* h1   = (_Float16*)(ws + (size_t)(27<<20) + 262144);            // 8 MB

  hipMemsetAsync(Bdeg, 0, NN*sizeof(int), stream);
  cvt_all_kernel<<<(NXG + 2*NWG)/256, 256, 0, stream>>>(x, W1, W2, xh, W1h, W2h);
  sumsq_np_kernel<<<NN/16, 256, 0, stream>>>(x, sqf);
  knn_kernel    <<<(NN/128)*NSLICE, 256, 0, stream>>>(xh, sqf, cand32);
  rescore_kernel<<<NN,     256, 0, stream>>>(x, sqf, cand32, idx, Bdeg);
  prefix_kernel <<<1,      256, 0, stream>>>(Bdeg, offE, cursor);
  fill_kernel   <<<NN/256, 256, 0, stream>>>(idx, cursor, rev);

  gemm_xw       <<<(NN/64)*4, 256, 0, stream>>>(xh, W1h, xt);
  efeat_kernel  <<<NN,        256, 0, stream>>>(xt, offE, Bdeg, rev, E);
  fin1_kernel   <<<NN,        256, 0, stream>>>(E, idx, b1, pa, h1);

  gemm_xw       <<<(NN/64)*4, 256, 0, stream>>>(h1, W2h, xt);
  efeat_kernel  <<<NN,        256, 0, stream>>>(xt, offE, Bdeg, rev, E);
  fin2_kernel   <<<NN,        256, 0, stream>>>(E, idx, b2, x, pa, out);
}

// Round 11
// 684.999 us; speedup vs baseline: 1.7631x; 1.2206x over previous
//
#include <hip/hip_runtime.h>
#include <stdint.h>

#define NN   16384
#define HID  256
#define LDSK 264            // padded LDS row stride in f16 elems (16B-aligned)
#define NSLICE 8
#define JSL  (NN/NSLICE)    // 2048 j's per slice
#define NRS  8              // exact-rescore chains (top-8 of 32 by float scan score)
#define FLTMAX 3.402823466e38f

typedef __attribute__((ext_vector_type(8))) _Float16 f16x8;
typedef __attribute__((ext_vector_type(4))) _Float16 f16x4;
typedef __attribute__((ext_vector_type(4))) float f32x4;

// ---- fused fp32 -> fp16 converter for x, W1, W2 (one launch) ----
#define NXG (NN*HID/4)
#define NWG (HID*HID/4)
__global__ __launch_bounds__(256) void cvt_all_kernel(const float* __restrict__ x,
                                                      const float* __restrict__ W1,
                                                      const float* __restrict__ W2,
                                                      _Float16* __restrict__ xh,
                                                      _Float16* __restrict__ W1h,
                                                      _Float16* __restrict__ W2h){
  int g = blockIdx.x * 256 + threadIdx.x;
  const float* src; _Float16* dst; int o;
  if (g < NXG)            { src = x;  dst = xh;  o = g; }
  else if (g < NXG + NWG) { src = W1; dst = W1h; o = g - NXG; }
  else                    { src = W2; dst = W2h; o = g - NXG - NWG; }
  float4 v = ((const float4*)src)[o];
  f16x4 h; h.x = (_Float16)v.x; h.y = (_Float16)v.y; h.z = (_Float16)v.z; h.w = (_Float16)v.w;
  ((f16x4*)dst)[o] = h;
}

// ---- row sum-of-squares, bit-replicating numpy fp32 pairwise summation ----
__global__ __launch_bounds__(256) void sumsq_np_kernel(const float* __restrict__ x,
                                                       float* __restrict__ sqf){
  #pragma clang fp contract(off)
  int lane = threadIdx.x & 63;
  int rw   = lane >> 4;
  int h    = (lane >> 3) & 1;
  int j    = lane & 7;
  int row  = (blockIdx.x * 4 + (threadIdx.x >> 6)) * 4 + rw;
  const float* p = x + (size_t)row * HID + h*128 + j;
  float v0 = p[0];
  float r  = v0 * v0;
  #pragma unroll
  for (int i = 1; i < 16; ++i){ float v = p[i*8]; float m = v * v; r = r + m; }
  float t1 = r  + __shfl_xor(r,  1);
  float t2 = t1 + __shfl_xor(t1, 2);
  float t3 = t2 + __shfl_xor(t2, 4);
  float tot = t3 + __shfl_xor(t3, 8);
  if (h == 0 && j == 0) sqf[row] = tot;
}

// stage 64x256 f16 tile into LDS with padded stride (256 threads)
__device__ __forceinline__ void load_tile64(unsigned short* dst, const unsigned short* src, int tid){
  const uint4* s = (const uint4*)src;
  #pragma unroll
  for (int r = 0; r < 8; ++r){
    int fl  = tid + (r << 8);
    int row = fl >> 5;
    int c   = fl & 31;
    *(uint4*)&dst[row*LDSK + (c << 3)] = s[fl];
  }
}

// running top-4 (smallest) insert, strict < (exact floats + index, R8-proven)
__device__ __forceinline__ void upd4(float (&bd)[4], int (&bi)[4], float d, int j){
  if (d < bd[3]){
    if      (d < bd[0]){ bd[3]=bd[2];bi[3]=bi[2]; bd[2]=bd[1];bi[2]=bi[1]; bd[1]=bd[0];bi[1]=bi[0]; bd[0]=d; bi[0]=j; }
    else if (d < bd[1]){ bd[3]=bd[2];bi[3]=bi[2]; bd[2]=bd[1];bi[2]=bi[1]; bd[1]=d; bi[1]=j; }
    else if (d < bd[2]){ bd[3]=bd[2];bi[3]=bi[2]; bd[2]=d; bi[2]=j; }
    else               { bd[3]=d; bi[3]=j; }
  }
}

// fp16 MFMA Gram, swapped operands (streamed j-tile first operand from LDS,
// stationary i-rows second; C col = i = lcol). FOUR stationary i-sets/wave:
// each LDS a-fragment feeds 4 independent MFMA chains -> LDS traffic /4 vs
// 1-set, high MFMA ILP. Scan state: exact float (v = sj - 2*dot, sq_i const
// per row dropped) + index, R8-proven semantics. i-tile 256/block, j sliced
// 8-way; outputs exact float score + j, 4 per (i, slice).
__global__ __launch_bounds__(256, 2) void knn_kernel(const _Float16* __restrict__ xh,
                                                     const float* __restrict__ sqf,
                                                     float* __restrict__ candd,
                                                     int* __restrict__ candj){
  __shared__ unsigned short Xj[64 * LDSK];   // 33792 B staging; aliased as merge buffer
  __shared__ float sqj[64];

  int tid  = threadIdx.x;
  int sl   = blockIdx.x & (NSLICE-1);
  int i0   = (blockIdx.x >> 3) * 256;
  int jb0  = sl * JSL;
  int wave = tid >> 6, lane = tid & 63, quad = lane >> 4, lcol = lane & 15;

  f16x8 bfr[4][8];
  int gi[4];
  #pragma unroll
  for (int s = 0; s < 4; ++s){
    gi[s] = i0 + s*64 + wave*16 + lcol;
    const _Float16* br = xh + (size_t)gi[s] * HID + quad*8;
    #pragma unroll
    for (int ks = 0; ks < 8; ++ks) bfr[s][ks] = *(const f16x8*)(br + ks*32);
  }

  float bd[4][4]; int bi[4][4];
  #pragma unroll
  for (int s = 0; s < 4; ++s)
    #pragma unroll
    for (int e = 0; e < 4; ++e){ bd[s][e] = FLTMAX; bi[s][e] = 0; }

  for (int it = 0; it < JSL; it += 64){
    int jb = jb0 + it;
    __syncthreads();
    load_tile64(Xj, (const unsigned short*)(xh + (size_t)jb * HID), tid);
    if (tid < 64) sqj[tid] = sqf[jb + tid];
    __syncthreads();

    #pragma unroll
    for (int sub = 0; sub < 4; ++sub){
      f32x4 acc[4];
      #pragma unroll
      for (int s = 0; s < 4; ++s) acc[s] = (f32x4){0.f,0.f,0.f,0.f};
      #pragma unroll
      for (int ks = 0; ks < 8; ++ks){
        f16x8 a = *(const f16x8*)&Xj[(sub*16 + lcol)*LDSK + quad*8 + ks*32];
        #pragma unroll
        for (int s = 0; s < 4; ++s)
          acc[s] = __builtin_amdgcn_mfma_f32_16x16x32_f16(a, bfr[s][ks], acc[s], 0, 0, 0);
      }
      // C: row = j-local-in-tile = quad*4+reg, col = i-local = lcol
      float4 sj4 = *(const float4*)&sqj[sub*16 + quad*4];
      int jbase = jb + sub*16 + quad*4;
      #pragma unroll
      for (int reg = 0; reg < 4; ++reg){
        int gj = jbase + reg;
        float sj = (&sj4.x)[reg];
        #pragma unroll
        for (int s = 0; s < 4; ++s){
          float v = (gj == gi[s]) ? FLTMAX : fmaf(-2.f, acc[s][reg], sj);
          upd4(bd[s], bi[s], v, gj);
        }
      }
    }
  }

  // merge across the 4 quads per i: 16 (score,j) -> top-4 (LDS aliased on Xj)
  __syncthreads();
  float* Md = (float*)Xj;                // 256 x 16 floats = 16 KB
  int*   Mi = (int*)Xj + 256*16;         // 256 x 16 ints   = 16 KB (32 KB <= 33792)
  #pragma unroll
  for (int s = 0; s < 4; ++s){
    int base = (s*64 + wave*16 + lcol)*16 + quad*4;
    #pragma unroll
    for (int e = 0; e < 4; ++e){ Md[base+e] = bd[s][e]; Mi[base+e] = bi[s][e]; }
  }
  __syncthreads();
  {
    float fd[4]; int fi[4];
    #pragma unroll
    for (int e = 0; e < 4; ++e){ fd[e] = FLTMAX; fi[e] = 0; }
    #pragma unroll
    for (int s = 0; s < 16; ++s) upd4(fd, fi, Md[tid*16 + s], Mi[tid*16 + s]);
    int g = i0 + tid;
    #pragma unroll
    for (int e = 0; e < 4; ++e){
      candd[(size_t)g*32 + sl*4 + e] = fd[e];
      candj[(size_t)g*32 + sl*4 + e] = fi[e];
    }
  }
}

// Rescore: rank the 32 exact-float scan scores (lex (score, j)), take top-8,
// stage those rows TRANSPOSED in LDS (conflict-free chains), run the exact
// np-replicating fp32 pipeline on them: dot = sequential-in-k fp32 FMA chain
// (OpenBLAS sgemm microkernel), d2 = fl32(fl32(sq_i+sq_j) - 2*dot).
// Final rank by (d2, index) lex. One wave per node.
__global__ __launch_bounds__(64) void rescore_kernel(const float* __restrict__ x,
                                                     const float* __restrict__ sqf,
                                                     const float* __restrict__ candd,
                                                     const int* __restrict__ candj,
                                                     int* __restrict__ idx_out,
                                                     int* __restrict__ Bdeg){
  #pragma clang fp contract(off)
  __shared__ float Xi[256];
  __shared__ float Xct[256][NRS+1];   // transposed candidate rows, 9.2 KB
  __shared__ float dex[NRS];
  __shared__ int   sel[NRS];
  int i = blockIdx.x;
  int t = threadIdx.x;            // 0..63
  ((float4*)Xi)[t] = ((const float4*)(x + (size_t)i * HID))[t];
  float dv = FLTMAX; int jv = 0x7fffffff;
  if (t < 32){ dv = candd[(size_t)i*32 + t]; jv = candj[(size_t)i*32 + t]; }
  int rank = 0;
  for (int s = 0; s < 32; ++s){
    float ds = __shfl(dv, s); int js = __shfl(jv, s);
    bool less = (ds < dv) || (ds == dv && js < jv);
    rank += less ? 1 : 0;
  }
  if (t < 32 && rank < NRS) sel[rank] = jv;
  __syncthreads();
  {
    int r = t >> 3, seg = t & 7;     // 8 rows x 8 segments
    const float4* src = (const float4*)(x + (size_t)sel[r] * HID);
    #pragma unroll
    for (int m = 0; m < 8; ++m){
      float4 v = src[seg + 8*m];
      int k = 4*(seg + 8*m);
      Xct[k+0][r] = v.x; Xct[k+1][r] = v.y; Xct[k+2][r] = v.z; Xct[k+3][r] = v.w;
    }
  }
  __syncthreads();
  if (t < NRS){
    int j = sel[t];
    float acc = 0.f;
    for (int k = 0; k < 256; ++k) acc = fmaf(Xi[k], Xct[k][t], acc);
    float t1   = sqf[i] + sqf[j];
    float twod = 2.0f * acc;
    dex[t] = t1 - twod;
  }
  __syncthreads();
  if (t == 0){
    unsigned taken = 0;
    #pragma unroll
    for (int k = 0; k < 4; ++k){
      float bdv = FLTMAX; int bj = 0x7fffffff, bs = -1;
      for (int s = 0; s < NRS; ++s){
        if (taken & (1u << s)) continue;
        float d = dex[s]; int j = sel[s];
        if (d < bdv || (d == bdv && j < bj)){ bdv = d; bj = j; bs = s; }
      }
      taken |= 1u << bs;
      idx_out[i*4 + k] = bj;
      atomicAdd(&Bdeg[bj], 1);
    }
  }
}

// out[i][o] = sum_k A[i][k] * W[o][k]   (A: Mx256 f16, W staged f16, out f16)
__global__ __launch_bounds__(256) void gemm_xw(const _Float16* __restrict__ A,
                                               const _Float16* __restrict__ W,
                                               _Float16* __restrict__ out){
  __shared__ unsigned short Ws[64 * LDSK];
  int tid = threadIdx.x;
  int i0 = (blockIdx.x >> 2) * 64;
  int o0 = (blockIdx.x & 3)  * 64;
  int wave = tid >> 6, lane = tid & 63, quad = lane >> 4, lcol = lane & 15;
  load_tile64(Ws, (const unsigned short*)(W + (size_t)o0 * HID), tid);
  f16x8 a[8];
  const _Float16* arow = A + (size_t)(i0 + wave*16 + lcol) * HID + quad*8;
  #pragma unroll
  for (int ks = 0; ks < 8; ++ks) a[ks] = *(const f16x8*)(arow + ks*32);
  __syncthreads();
  #pragma unroll
  for (int sub = 0; sub < 4; ++sub){
    f32x4 acc = {0.f, 0.f, 0.f, 0.f};
    #pragma unroll
    for (int ks = 0; ks < 8; ++ks){
      f16x8 b = *(const f16x8*)&Ws[(sub*16 + lcol)*LDSK + quad*8 + ks*32];
      acc = __builtin_amdgcn_mfma_f32_16x16x32_f16(a[ks], b, acc, 0, 0, 0);
    }
    #pragma unroll
    for (int reg = 0; reg < 4; ++reg)
      out[(size_t)(i0 + wave*16 + quad*4 + reg)*HID + o0 + sub*16 + lcol] = (_Float16)acc[reg];
  }
}

__global__ __launch_bounds__(256) void prefix_kernel(const int* __restrict__ Bdeg,
                                                     int* __restrict__ off,
                                                     int* __restrict__ cursor){
  __shared__ int psum[256];
  __shared__ int excl[256];
  int t = threadIdx.x;
  int base = t * 64;
  int s = 0;
  for (int k = 0; k < 64; ++k) s += Bdeg[base + k];
  psum[t] = s;
  __syncthreads();
  if (t == 0){ int a = 0; for (int k = 0; k < 256; ++k){ excl[k] = a; a += psum[k]; } }
  __syncthreads();
  int a = excl[t];
  for (int k = 0; k < 64; ++k){ int dv = Bdeg[base + k]; off[base+k] = a; cursor[base+k] = a; a += dv; }
}

__global__ __launch_bounds__(256) void fill_kernel(const int* __restrict__ idx,
                                                   int* __restrict__ cursor,
                                                   int* __restrict__ rev){
  int i = blockIdx.x * 256 + threadIdx.x;
  #pragma unroll
  for (int t = 0; t < 4; ++t){
    int e = idx[i*4 + t];
    int p = atomicAdd(&cursor[e], 1);
    rev[p] = i;
  }
}

// E[e] = mean over contributing nodes of xt[node]  (gather via reverse CSR)
__global__ __launch_bounds__(256) void efeat_kernel(const _Float16* __restrict__ xt,
                                                    const int* __restrict__ off,
                                                    const int* __restrict__ deg,
                                                    const int* __restrict__ rev,
                                                    _Float16* __restrict__ E){
  int e = blockIdx.x, c = threadIdx.x;
  int o = off[e], d = deg[e];
  float s = 0.f;
  for (int k = 0; k < d; ++k) s += (float)xt[(size_t)rev[o + k]*HID + c];
  E[(size_t)e*HID + c] = (_Float16)((d > 0) ? s / (float)d : 0.f);
}

__global__ __launch_bounds__(256) void fin1_kernel(const _Float16* __restrict__ E,
                                                   const int* __restrict__ idx,
                                                   const float* __restrict__ b1,
                                                   const float* __restrict__ pa,
                                                   _Float16* __restrict__ h1){
  int i = blockIdx.x, c = threadIdx.x;
  const int* ip = idx + i*4;
  float s = (float)E[(size_t)ip[0]*HID + c] + (float)E[(size_t)ip[1]*HID + c]
          + (float)E[(size_t)ip[2]*HID + c] + (float)E[(size_t)ip[3]*HID + c];
  float acc = 0.25f * s + b1[c];
  float a = pa[0];
  acc = (acc >= 0.f) ? acc : a * acc;
  h1[(size_t)i*HID + c] = (_Float16)acc;
}

__global__ __launch_bounds__(256) void fin2_kernel(const _Float16* __restrict__ E,
                                                   const int* __restrict__ idx,
                                                   const float* __restrict__ b2,
                                                   const float* __restrict__ x,
                                                   const float* __restrict__ pa,
                                                   float* __restrict__ out){
  int i = blockIdx.x, c = threadIdx.x;
  const int* ip = idx + i*4;
  float s = (float)E[(size_t)ip[0]*HID + c] + (float)E[(size_t)ip[1]*HID + c]
          + (float)E[(size_t)ip[2]*HID + c] + (float)E[(size_t)ip[3]*HID + c];
  float acc = 0.25f * s + b2[c] + x[(size_t)i*HID + c];
  float a = pa[0];
  acc = (acc >= 0.f) ? acc : a * acc;
  out[(size_t)i*HID + c] = acc;
}

extern "C" void kernel_launch(void* const* d_in, const int* in_sizes, int n_in,
                              void* d_out, int out_size, void* d_ws, size_t ws_size,
                              hipStream_t stream){
  (void)in_sizes; (void)n_in; (void)out_size; (void)ws_size;
  const float* x  = (const float*)d_in[0];
  // d_in[1] = edge_index (int32), unused by the math
  const float* W1 = (const float*)d_in[2];
  const float* b1 = (const float*)d_in[3];
  const float* W2 = (const float*)d_in[4];
  const float* b2 = (const float*)d_in[5];
  const float* pa = (const float*)d_in[6];
  float* out = (float*)d_out;

  char* ws = (char*)d_ws;
  float*  sqf    = (float*) (ws + 0);                        //  64 KB
  int*    idx    = (int*)   (ws + 65536);                    // 256 KB
  int*    Bdeg   = (int*)   (ws + 327680);                   //  64 KB
  int*    offE   = (int*)   (ws + 393216);                   //  64 KB
  int*    cursor = (int*)   (ws + 458752);                   //  64 KB
  int*    rev    = (int*)   (ws + 524288);                   // 256 KB
  float*  candd  = (float*) (ws + (size_t)(1<<20));          //   2 MB
  int*    candj  = (int*)   (ws + (size_t)(3<<20));          //   2 MB
  _Float16* xh   = (_Float16*)(ws + (size_t)(5<<20));        //   8 MB
  _Float16* W1h  = (_Float16*)(ws + (size_t)(13<<20));       // 128 KB
  _Float16* W2h  = (_Float16*)(ws + (size_t)(13<<20) + 131072);
  _Float16* xt   = (_Float16*)(ws + (size_t)(13<<20) + 262144);            // 8 MB
  _Float16* E    = (_Float16*)(ws + (size_t)(21<<20) + 262144);            // 8 MB
  _Float16* h1   = (_Float16*)(ws + (size_t)(29<<20) + 262144);            // 8 MB

  hipMemsetAsync(Bdeg, 0, NN*sizeof(int), stream);
  cvt_all_kernel<<<(NXG + 2*NWG)/256, 256, 0, stream>>>(x, W1, W2, xh, W1h, W2h);
  sumsq_np_kernel<<<NN/16, 256, 0, stream>>>(x, sqf);
  knn_kernel    <<<(NN/256)*NSLICE, 256, 0, stream>>>(xh, sqf, candd, candj);
  rescore_kernel<<<NN,      64, 0, stream>>>(x, sqf, candd, candj, idx, Bdeg);
  prefix_kernel <<<1,      256, 0, stream>>>(Bdeg, offE, cursor);
  fill_kernel   <<<NN/256, 256, 0, stream>>>(idx, cursor, rev);

  gemm_xw       <<<(NN/64)*4, 256, 0, stream>>>(xh, W1h, xt);
  efeat_kernel  <<<NN,        256, 0, stream>>>(xt, offE, Bdeg, rev, E);
  fin1_kernel   <<<NN,        256, 0, stream>>>(E, idx, b1, pa, h1);

  gemm_xw       <<<(NN/64)*4, 256, 0, stream>>>(h1, W2h, xt);
  efeat_kernel  <<<NN,        256, 0, stream>>>(xt, offE, Bdeg, rev, E);
  fin2_kernel   <<<NN,        256, 0, stream>>>(E, idx, b2, x, pa, out);
}